// Round 8
// baseline (71.217 us; speedup 1.0000x reference)
//
#include <hip/hip_runtime.h>
#include <hip/hip_bf16.h>
#include <cstdint>

#define SS   2048
#define DD   128
#define KBLK 64
#define NKT  32                      // key tiles per batch
#define TILE_BYTES 16384             // one tile: 64 keys x 128 d bf16 (frag-ordered)

#define NBLK 1152                    // CHUNK=4 blocks
#define WS_K    ((size_t)0)
#define WS_V    ((size_t)16 * NKT * TILE_BYTES)             // 8 MB
#define WS_PO   ((size_t)16 * NKT * TILE_BYTES * 2)         // 16 MB
#define WS_ML   (WS_PO + (size_t)NBLK * 128 * 128 * 2)      // +37.75 MB
#define WS_NEED (WS_ML + (size_t)NBLK * 128 * 4)            // ~54.9 MB

typedef __attribute__((ext_vector_type(8)))  short short8;   // 8 bf16 (MFMA A/B)
typedef __attribute__((ext_vector_type(16))) float f32x16;   // 32x32 MFMA C/D
typedef __attribute__((ext_vector_type(4)))  float f32x4;

__device__ __forceinline__ unsigned short f2bf(float x) {
  return __builtin_bit_cast(unsigned short, (__bf16)x);
}
__device__ __forceinline__ float bfbits2f(unsigned int lo16shifted) {
  return __builtin_bit_cast(float, lo16shifted);
}

// ---- chunk tables: q-block i has 2i+2 tiles, chunks of <=4 ----
__device__ __constant__ unsigned char SLOT_BASE[16] = {0,1,2,4,6,9,12,16,20,25,30,36,42,49,56,64};
__device__ __constant__ unsigned char NCH[16]       = {1,1,2,2,3,3,4,4,5,5,6,6,7,7,8,8};
__device__ __constant__ unsigned char SLOT_I[72] = {
  0,1,2,2,3,3,4,4,4,5,5,5,6,6,6,6,7,7,7,7,
  8,8,8,8,8,9,9,9,9,9,10,10,10,10,10,10,11,11,11,11,11,11,
  12,12,12,12,12,12,12,13,13,13,13,13,13,13,
  14,14,14,14,14,14,14,14,15,15,15,15,15,15,15,15};

// ---------------------------------------------------------------------------
// Pre-pass: emit FRAGMENT-ORDERED bf16 tiles so the main kernel's per-wave
// MFMA operand loads are single coalesced 1KB global_load_dwordx4 from L2.
//   K tile entry e = g*512 + s*64 + lane (lane = h*32+l31), 16B =
//     K[key = g*32+l31][d = s*16+h*8 .. +8)
//   V tile entry e = (dg*4+s4)*64 + lane, 16B =
//     V^T[d = dg*32+l31][slot = (s4*2+h)*8 + j],  slot -> key via pi (a(y8,j))
// ---------------------------------------------------------------------------
__global__ __launch_bounds__(256) void prepack_kv8(
    const float* __restrict__ K, const float* __restrict__ V, char* __restrict__ ws)
{
  __shared__ float st[64][132];   // 132: row stride 528B = 16-aligned
  const int b = blockIdx.x, t = blockIdx.y;
  const int tid = threadIdx.x;
  const float* Kt = K + ((size_t)b * SS + t * KBLK) * DD;
  const float* Vt = V + ((size_t)b * SS + t * KBLK) * DD;
  char* Kd = ws + WS_K + ((size_t)(b * NKT + t)) * TILE_BYTES;
  char* Vd = ws + WS_V + ((size_t)(b * NKT + t)) * TILE_BYTES;

  // ---- K: stage f32 tile to LDS (coalesced) ----
  #pragma unroll
  for (int u = 0; u < 4; ++u) {
    int row = u * 16 + (tid >> 4);
    int col = 8 * (tid & 15);
    const float4* sp = reinterpret_cast<const float4*>(Kt + (size_t)row * DD + col);
    float4 x = sp[0], y = sp[1];
    *reinterpret_cast<float4*>(&st[row][col])     = x;
    *reinterpret_cast<float4*>(&st[row][col + 4]) = y;
  }
  __syncthreads();
  // scatter K fragments (coalesced 16B writes)
  #pragma unroll
  for (int u = 0; u < 4; ++u) {
    int e = u * 256 + tid;
    int g = e >> 9, s = (e >> 6) & 7, lane = e & 63;
    int h = lane >> 5, l31 = lane & 31;
    int key = g * 32 + l31;
    int d0 = s * 16 + h * 8;
    float4 x = *reinterpret_cast<const float4*>(&st[key][d0]);
    float4 y = *reinterpret_cast<const float4*>(&st[key][d0 + 4]);
    short8 w;
    w[0] = f2bf(x.x); w[1] = f2bf(x.y); w[2] = f2bf(x.z); w[3] = f2bf(x.w);
    w[4] = f2bf(y.x); w[5] = f2bf(y.y); w[6] = f2bf(y.z); w[7] = f2bf(y.w);
    *reinterpret_cast<short8*>(Kd + e * 16) = w;
  }
  __syncthreads();

  // ---- V: stage f32 tile to LDS ----
  #pragma unroll
  for (int u = 0; u < 4; ++u) {
    int row = u * 16 + (tid >> 4);
    int col = 8 * (tid & 15);
    const float4* sp = reinterpret_cast<const float4*>(Vt + (size_t)row * DD + col);
    float4 x = sp[0], y = sp[1];
    *reinterpret_cast<float4*>(&st[row][col])     = x;
    *reinterpret_cast<float4*>(&st[row][col + 4]) = y;
  }
  __syncthreads();
  // scatter V^T fragments (pi-permuted slots)
  #pragma unroll
  for (int u = 0; u < 4; ++u) {
    int e = u * 256 + tid;
    int dg = e >> 8, s4 = (e >> 6) & 3, lane = e & 63;
    int h = lane >> 5, l31 = lane & 31;
    int d = dg * 32 + l31;
    int y8 = s4 * 2 + h;
    short8 w;
    #pragma unroll
    for (int j = 0; j < 8; ++j) {
      int a = ((y8 >> 2) << 5) | (((y8 >> 1) & 1) << 4) | ((j >> 2) << 3) | (j & 3) | ((y8 & 1) << 2);
      w[j] = f2bf(st[a][d]);
    }
    *reinterpret_cast<short8*>(Vd + e * 16) = w;
  }
}

// ---------------------------------------------------------------------------
// Main: ZERO LDS, ZERO barriers. Each wave reads its MFMA fragments directly
// from the frag-ordered L2-resident tiles (coalesced 1KB loads). Waves
// free-run; latency hidden by load ILP + co-resident waves.
// ---------------------------------------------------------------------------
__global__ __launch_bounds__(256) void sdpa_v8(
    const float* __restrict__ Q, const char* __restrict__ ws,
    float* __restrict__ O, unsigned short* __restrict__ partO,
    float* __restrict__ partML)
{
  const int y = blockIdx.x;
  const int b = y & 15;
  const int slot = y >> 4;
  const int i = SLOT_I[slot];
  const int c = slot - SLOT_BASE[i];
  const int nch = NCH[i];
  const int ntile = (c == nch - 1) ? (2 * i + 2 - 4 * c) : 4;
  const int kvt0 = 4 * c;
  const bool dostore = (nch == 1);

  const int tid  = threadIdx.x;
  const int lane = tid & 63;
  const int wid  = tid >> 6;
  const int l31  = lane & 31;
  const int h    = lane >> 5;

  const float* Qb  = Q + (size_t)b * SS * DD;
  const char*  Kws = ws + WS_K + ((size_t)(b * NKT)) * TILE_BYTES;
  const char*  Vws = ws + WS_V + ((size_t)(b * NKT)) * TILE_BYTES;

  const float qscale = 0.08838834764831845f * 1.4426950408889634f; // 1/sqrt(128)*log2e
  const int qg = 128 * i + wid * 32 + l31;

  // Q fragments (B-operand), scale folded
  short8 qf[8];
  {
    const float* qrow = Qb + (size_t)qg * DD;
    #pragma unroll
    for (int s = 0; s < 8; ++s) {
      const float4* p = reinterpret_cast<const float4*>(qrow + s * 16 + h * 8);
      float4 x = p[0], z = p[1];
      short8 w;
      w[0] = f2bf(x.x * qscale); w[1] = f2bf(x.y * qscale);
      w[2] = f2bf(x.z * qscale); w[3] = f2bf(x.w * qscale);
      w[4] = f2bf(z.x * qscale); w[5] = f2bf(z.y * qscale);
      w[6] = f2bf(z.z * qscale); w[7] = f2bf(z.w * qscale);
      qf[s] = w;
    }
  }

  f32x16 o[4];
  #pragma unroll
  for (int dg = 0; dg < 4; ++dg)
    #pragma unroll
    for (int r = 0; r < 16; ++r) o[dg][r] = 0.f;
  float lsum = 0.f;

  for (int t = 0; t < ntile; ++t) {
    const int tt = kvt0 + t;
    const char* Kt = Kws + (size_t)tt * TILE_BYTES;
    const char* Vt = Vws + (size_t)tt * TILE_BYTES;
    const bool domask = tt >= 2 * i;

    short8 pf[4];
    float psum = 0.f;

    // ---- QK^T per key-group g (32 keys) ----
    #pragma unroll
    for (int g = 0; g < 2; ++g) {
      short8 kf[8];
      #pragma unroll
      for (int s = 0; s < 8; ++s)
        kf[s] = *reinterpret_cast<const short8*>(Kt + g * 8192 + s * 1024 + lane * 16);

      f32x16 acc;
      #pragma unroll
      for (int r = 0; r < 16; ++r) acc[r] = 0.f;
      __builtin_amdgcn_s_setprio(1);
      #pragma unroll
      for (int s = 0; s < 8; ++s)
        acc = __builtin_amdgcn_mfma_f32_32x32x16_bf16(kf[s], qf[s], acc, 0, 0, 0);
      __builtin_amdgcn_s_setprio(0);

      if (domask) {
        const int kb = tt * 64 + g * 32 + 4 * h;
        #pragma unroll
        for (int r = 0; r < 16; ++r) {
          int keyg = kb + (r & 3) + 8 * (r >> 2);
          if (keyg > qg) acc[r] = -1e30f;
        }
      }

      float pg[16];
      #pragma unroll
      for (int r = 0; r < 16; ++r) pg[r] = exp2f(acc[r]);
      float s0 = ((pg[0]+pg[1])+(pg[2]+pg[3])) + ((pg[4]+pg[5])+(pg[6]+pg[7]));
      float s1 = ((pg[8]+pg[9])+(pg[10]+pg[11])) + ((pg[12]+pg[13])+(pg[14]+pg[15]));
      psum += s0 + s1;

      short8 w0, w1;
      #pragma unroll
      for (int j = 0; j < 8; ++j) { w0[j] = f2bf(pg[j]); w1[j] = f2bf(pg[8 + j]); }
      pf[2 * g]     = w0;
      pf[2 * g + 1] = w1;
    }
    lsum += psum;

    // ---- PV: O^T[d][q] += Vt . P  (A-frag slots == lane's own P regs) ----
    #pragma unroll
    for (int dg = 0; dg < 4; ++dg) {
      short8 vf[4];
      #pragma unroll
      for (int s4 = 0; s4 < 4; ++s4)
        vf[s4] = *reinterpret_cast<const short8*>(Vt + (dg * 4 + s4) * 1024 + lane * 16);
      __builtin_amdgcn_s_setprio(1);
      #pragma unroll
      for (int s4 = 0; s4 < 4; ++s4)
        o[dg] = __builtin_amdgcn_mfma_f32_32x32x16_bf16(vf[s4], pf[s4], o[dg], 0, 0, 0);
      __builtin_amdgcn_s_setprio(0);
    }
  }

  // ---- epilogue ----
  lsum += __shfl_xor(lsum, 32);

  if (dostore) {
    float inv = 1.0f / lsum;
    float* Ob = O + (size_t)b * SS * DD + (size_t)qg * DD;
    #pragma unroll
    for (int dg = 0; dg < 4; ++dg)
      #pragma unroll
      for (int rq = 0; rq < 4; ++rq) {
        int d0 = dg * 32 + 8 * rq + 4 * h;
        float4 w;
        w.x = o[dg][4 * rq + 0] * inv;
        w.y = o[dg][4 * rq + 1] * inv;
        w.z = o[dg][4 * rq + 2] * inv;
        w.w = o[dg][4 * rq + 3] * inv;
        *reinterpret_cast<float4*>(Ob + d0) = w;
      }
  } else {
    unsigned short* po = partO + (size_t)y * (128 * 128) + (size_t)(wid * 32 + l31) * 128;
    #pragma unroll
    for (int dg = 0; dg < 4; ++dg)
      #pragma unroll
      for (int rq = 0; rq < 4; ++rq) {
        int d0 = dg * 32 + 8 * rq + 4 * h;
        ushort4 u;
        u.x = f2bf(o[dg][4 * rq + 0]);
        u.y = f2bf(o[dg][4 * rq + 1]);
        u.z = f2bf(o[dg][4 * rq + 2]);
        u.w = f2bf(o[dg][4 * rq + 3]);
        *reinterpret_cast<ushort4*>(po + d0) = u;
      }
    if (h == 0) partML[y * 128 + wid * 32 + l31] = lsum;
  }
}

// ---------------------------------------------------------------------------
// Merge for i>=2: O[b][128i+row][:] = (sum_c U_c) / (sum_c l_c)
// ---------------------------------------------------------------------------
__global__ __launch_bounds__(256) void merge_v8(
    const unsigned short* __restrict__ partO, const float* __restrict__ partML,
    float* __restrict__ O)
{
  const int b = blockIdx.x;
  const int i = blockIdx.y + 2;
  const int rg = blockIdx.z;
  const int tid = threadIdx.x;
  const int row = rg * 32 + (tid >> 3);
  const int c0  = (tid & 7) * 16;

  float acc[16];
  #pragma unroll
  for (int u = 0; u < 16; ++u) acc[u] = 0.f;
  float ltot = 0.f;

  const int nch = NCH[i];
  const int base = SLOT_BASE[i];

  for (int c = 0; c < nch; ++c) {
    int slot = (base + c) * 16 + b;
    ltot += partML[slot * 128 + row];
    const uint4* po = reinterpret_cast<const uint4*>(
        partO + (size_t)slot * (128 * 128) + (size_t)row * 128 + c0);
    #pragma unroll
    for (int u = 0; u < 2; ++u) {
      uint4 v = po[u];
      acc[u*8+0] += bfbits2f(v.x << 16); acc[u*8+1] += bfbits2f(v.x & 0xffff0000u);
      acc[u*8+2] += bfbits2f(v.y << 16); acc[u*8+3] += bfbits2f(v.y & 0xffff0000u);
      acc[u*8+4] += bfbits2f(v.z << 16); acc[u*8+5] += bfbits2f(v.z & 0xffff0000u);
      acc[u*8+6] += bfbits2f(v.w << 16); acc[u*8+7] += bfbits2f(v.w & 0xffff0000u);
    }
  }
  float inv = 1.0f / ltot;
  float* orow = O + ((size_t)b * SS + 128 * i + row) * DD + c0;
  #pragma unroll
  for (int u = 0; u < 4; ++u) {
    float4 w;
    w.x = acc[4*u+0] * inv; w.y = acc[4*u+1] * inv;
    w.z = acc[4*u+2] * inv; w.w = acc[4*u+3] * inv;
    reinterpret_cast<float4*>(orow)[u] = w;
  }
}

// ---------------------------------------------------------------------------
// Emergency fallback (round-1 style, no ws) if workspace too small
// ---------------------------------------------------------------------------
__device__ __forceinline__ int sigma_col(int a) {
  return (a & 35) | ((a & 12) << 1) | ((a & 16) >> 2);
}

__global__ __launch_bounds__(256) void sdpa_naive(
    const float* __restrict__ Q, const float* __restrict__ K,
    const float* __restrict__ V, float* __restrict__ O)
{
  __shared__ __align__(16) char smem[64 * 128 * 2 * 2];
  char* Klds  = smem;
  char* Vtlds = smem + 64 * 128 * 2;

  const int b   = blockIdx.x;
  const int qb  = (int)gridDim.y - 1 - (int)blockIdx.y;
  const int q0  = qb * 64;
  const int tid = threadIdx.x;
  const int lane = tid & 63;
  const int wid  = tid >> 6;
  const int l15  = lane & 15;
  const int hi   = lane >> 4;

  const float* Qb = Q + (size_t)b * SS * DD;
  const float* Kb = K + (size_t)b * SS * DD;
  const float* Vb = V + (size_t)b * SS * DD;
  float*       Ob = O + (size_t)b * SS * DD;
  const float scale = 0.08838834764831845f;

  short8 qf[4];
  {
    const float* qrow = Qb + (size_t)(q0 + wid * 16 + l15) * DD;
    #pragma unroll
    for (int cc = 0; cc < 4; ++cc) {
      const float4* p = reinterpret_cast<const float4*>(qrow + 32 * cc + 8 * hi);
      float4 x = p[0], yv = p[1];
      short8 w;
      w[0]=f2bf(x.x*scale); w[1]=f2bf(x.y*scale); w[2]=f2bf(x.z*scale); w[3]=f2bf(x.w*scale);
      w[4]=f2bf(yv.x*scale); w[5]=f2bf(yv.y*scale); w[6]=f2bf(yv.z*scale); w[7]=f2bf(yv.w*scale);
      qf[cc] = w;
    }
  }

  f32x4 o[8];
  #pragma unroll
  for (int nt = 0; nt < 8; ++nt) o[nt] = (f32x4){0.f,0.f,0.f,0.f};
  float m = -INFINITY, lsum = 0.f;

  const int ntile = qb + 1;
  for (int t = 0; t < ntile; ++t) {
    const int kv0 = t * 64;
    if (t) __syncthreads();
    #pragma unroll
    for (int u = 0; u < 4; ++u) {
      int row = u * 16 + (tid >> 4);
      int col = 8 * (tid & 15);
      const float4* sp = reinterpret_cast<const float4*>(Kb + (size_t)(kv0 + row) * DD + col);
      float4 x = sp[0], yv = sp[1];
      short8 w;
      w[0]=f2bf(x.x); w[1]=f2bf(x.y); w[2]=f2bf(x.z); w[3]=f2bf(x.w);
      w[4]=f2bf(yv.x); w[5]=f2bf(yv.y); w[6]=f2bf(yv.z); w[7]=f2bf(yv.w);
      int off = (row * 256 + col * 2) ^ ((row & 7) << 4);
      *reinterpret_cast<short8*>(Klds + off) = w;
    }
    #pragma unroll
    for (int u = 0; u < 4; ++u) {
      int row = u * 16 + (tid >> 4);
      int col = 8 * (tid & 15);
      const float4* sp = reinterpret_cast<const float4*>(Vb + (size_t)(kv0 + row) * DD + col);
      float4 x = sp[0], yv = sp[1];
      int sc = sigma_col(row);
      float vals[8] = {x.x, x.y, x.z, x.w, yv.x, yv.y, yv.z, yv.w};
      #pragma unroll
      for (int j = 0; j < 8; ++j) {
        int d = col + j;
        int off = ((d << 7) + (sc << 1)) ^ ((((d >> 3) ^ d) & 7) << 4);
        *reinterpret_cast<unsigned short*>(Vtlds + off) = f2bf(vals[j]);
      }
    }
    __syncthreads();

    f32x4 sacc[4];
    #pragma unroll
    for (int g = 0; g < 4; ++g) {
      f32x4 acc = {0.f,0.f,0.f,0.f};
      #pragma unroll
      for (int cc = 0; cc < 4; ++cc) {
        int row = g * 16 + l15;
        int off = (row * 256 + (32 * cc + 8 * hi) * 2) ^ ((row & 7) << 4);
        short8 kf = *reinterpret_cast<const short8*>(Klds + off);
        acc = __builtin_amdgcn_mfma_f32_16x16x32_bf16(kf, qf[cc], acc, 0, 0, 0);
      }
      sacc[g] = acc;
    }
    if (t == ntile - 1) {
      const int q = q0 + wid * 16 + l15;
      #pragma unroll
      for (int g = 0; g < 4; ++g)
        #pragma unroll
        for (int ii = 0; ii < 4; ++ii) {
          int key = kv0 + g * 16 + 4 * hi + ii;
          if (key > q) sacc[g][ii] = -1e30f;
        }
    }
    float tmax = -INFINITY;
    #pragma unroll
    for (int g = 0; g < 4; ++g)
      #pragma unroll
      for (int ii = 0; ii < 4; ++ii) tmax = fmaxf(tmax, sacc[g][ii]);
    tmax = fmaxf(tmax, __shfl_xor(tmax, 16));
    tmax = fmaxf(tmax, __shfl_xor(tmax, 32));
    float mnew = fmaxf(m, tmax);
    float corr = __expf(m - mnew);
    m = mnew;
    float p[4][4]; float psum = 0.f;
    #pragma unroll
    for (int g = 0; g < 4; ++g)
      #pragma unroll
      for (int ii = 0; ii < 4; ++ii) {
        float pv = __expf(sacc[g][ii] - mnew);
        p[g][ii] = pv; psum += pv;
      }
    psum += __shfl_xor(psum, 16);
    psum += __shfl_xor(psum, 32);
    lsum = lsum * corr + psum;
    float corrO[4];
    #pragma unroll
    for (int ii = 0; ii < 4; ++ii) corrO[ii] = __shfl(corr, 4 * hi + ii);
    #pragma unroll
    for (int nt = 0; nt < 8; ++nt)
      #pragma unroll
      for (int ii = 0; ii < 4; ++ii) o[nt][ii] *= corrO[ii];
    short8 pfr[2];
    #pragma unroll
    for (int ks = 0; ks < 2; ++ks) {
      short8 w;
      #pragma unroll
      for (int ii = 0; ii < 4; ++ii) { w[ii] = f2bf(p[2*ks][ii]); w[4+ii] = f2bf(p[2*ks+1][ii]); }
      pfr[ks] = w;
    }
    #pragma unroll
    for (int ks = 0; ks < 2; ++ks)
      #pragma unroll
      for (int nt = 0; nt < 8; ++nt) {
        int d = nt * 16 + l15;
        int off = ((d << 7) + (ks * 32 + 8 * hi) * 2) ^ ((((d >> 3) ^ d) & 7) << 4);
        short8 vvf = *reinterpret_cast<const short8*>(Vtlds + off);
        o[nt] = __builtin_amdgcn_mfma_f32_16x16x32_bf16(pfr[ks], vvf, o[nt], 0, 0, 0);
      }
  }
  float rl = 1.0f / lsum;
  float rlO[4];
  #pragma unroll
  for (int ii = 0; ii < 4; ++ii) rlO[ii] = __shfl(rl, 4 * hi + ii);
  const int qrow = q0 + wid * 16;
  #pragma unroll
  for (int nt = 0; nt < 8; ++nt)
    #pragma unroll
    for (int ii = 0; ii < 4; ++ii)
      Ob[(size_t)(qrow + 4 * hi + ii) * DD + nt * 16 + l15] = o[nt][ii] * rlO[ii];
}

extern "C" void kernel_launch(void* const* d_in, const int* in_sizes, int n_in,
                              void* d_out, int out_size, void* d_ws, size_t ws_size,
                              hipStream_t stream) {
  const float* Q = (const float*)d_in[0];
  const float* K = (const float*)d_in[1];
  const float* V = (const float*)d_in[2];
  float* O = (float*)d_out;
  char* ws = (char*)d_ws;

  if (ws_size >= WS_NEED) {
    unsigned short* partO = (unsigned short*)(ws + WS_PO);
    float* partML = (float*)(ws + WS_ML);
    prepack_kv8<<<dim3(16, NKT), 256, 0, stream>>>(K, V, ws);
    sdpa_v8<<<dim3(NBLK), 256, 0, stream>>>(Q, ws, O, partO, partML);
    merge_v8<<<dim3(16, 14, 4), 256, 0, stream>>>(partO, partML, O);
  } else {
    sdpa_naive<<<dim3(16, 32), 256, 0, stream>>>(Q, K, V, O);
  }
}

// Round 9
// 71.048 us; speedup vs baseline: 1.0024x; 1.0024x over previous
//
#include <hip/hip_runtime.h>
#include <hip/hip_bf16.h>
#include <cstdint>

#define SS   2048
#define DD   128
#define KBLK 64
#define NKT  32                      // key tiles per batch
#define TILE_BYTES 16384             // one tile: 64 keys x 128 d bf16 (frag-ordered)

#define NBLK 1152                    // CHUNK=4 blocks
#define WS_K    ((size_t)0)
#define WS_V    ((size_t)16 * NKT * TILE_BYTES)             // 8 MB
#define WS_PO   ((size_t)16 * NKT * TILE_BYTES * 2)         // 16 MB
#define WS_ML   (WS_PO + (size_t)NBLK * 128 * 128 * 2)      // +37.75 MB
#define WS_NEED (WS_ML + (size_t)NBLK * 128 * 4)            // ~54.9 MB

typedef __attribute__((ext_vector_type(8)))  short short8;   // 8 bf16 (MFMA A/B)
typedef __attribute__((ext_vector_type(16))) float f32x16;   // 32x32 MFMA C/D
typedef __attribute__((ext_vector_type(4)))  float f32x4;

__device__ __forceinline__ unsigned short f2bf(float x) {
  return __builtin_bit_cast(unsigned short, (__bf16)x);
}
__device__ __forceinline__ float bfbits2f(unsigned int lo16shifted) {
  return __builtin_bit_cast(float, lo16shifted);
}

// ---- chunk tables: q-block i has 2i+2 tiles, chunks of <=4 ----
__device__ __constant__ unsigned char SLOT_BASE[16] = {0,1,2,4,6,9,12,16,20,25,30,36,42,49,56,64};
__device__ __constant__ unsigned char NCH[16]       = {1,1,2,2,3,3,4,4,5,5,6,6,7,7,8,8};
__device__ __constant__ unsigned char SLOT_I[72] = {
  0,1,2,2,3,3,4,4,4,5,5,5,6,6,6,6,7,7,7,7,
  8,8,8,8,8,9,9,9,9,9,10,10,10,10,10,10,11,11,11,11,11,11,
  12,12,12,12,12,12,12,13,13,13,13,13,13,13,
  14,14,14,14,14,14,14,14,15,15,15,15,15,15,15,15};

// ---------------------------------------------------------------------------
// Pre-pass: FRAGMENT-ORDERED bf16 tiles (unchanged from v8).
//   K tile entry e = g*512 + s*64 + lane, 16B = K[g*32+l31][s*16+h*8 ..]
//   V tile entry e = (dg*4+s4)*64 + lane, 16B = V^T[dg*32+l31][pi-slots]
// ---------------------------------------------------------------------------
__global__ __launch_bounds__(256) void prepack_kv9(
    const float* __restrict__ K, const float* __restrict__ V, char* __restrict__ ws)
{
  __shared__ float st[64][132];
  const int b = blockIdx.x, t = blockIdx.y;
  const int tid = threadIdx.x;
  const float* Kt = K + ((size_t)b * SS + t * KBLK) * DD;
  const float* Vt = V + ((size_t)b * SS + t * KBLK) * DD;
  char* Kd = ws + WS_K + ((size_t)(b * NKT + t)) * TILE_BYTES;
  char* Vd = ws + WS_V + ((size_t)(b * NKT + t)) * TILE_BYTES;

  #pragma unroll
  for (int u = 0; u < 4; ++u) {
    int row = u * 16 + (tid >> 4);
    int col = 8 * (tid & 15);
    const float4* sp = reinterpret_cast<const float4*>(Kt + (size_t)row * DD + col);
    float4 x = sp[0], y = sp[1];
    *reinterpret_cast<float4*>(&st[row][col])     = x;
    *reinterpret_cast<float4*>(&st[row][col + 4]) = y;
  }
  __syncthreads();
  #pragma unroll
  for (int u = 0; u < 4; ++u) {
    int e = u * 256 + tid;
    int g = e >> 9, s = (e >> 6) & 7, lane = e & 63;
    int h = lane >> 5, l31 = lane & 31;
    int key = g * 32 + l31;
    int d0 = s * 16 + h * 8;
    float4 x = *reinterpret_cast<const float4*>(&st[key][d0]);
    float4 y = *reinterpret_cast<const float4*>(&st[key][d0 + 4]);
    short8 w;
    w[0] = f2bf(x.x); w[1] = f2bf(x.y); w[2] = f2bf(x.z); w[3] = f2bf(x.w);
    w[4] = f2bf(y.x); w[5] = f2bf(y.y); w[6] = f2bf(y.z); w[7] = f2bf(y.w);
    *reinterpret_cast<short8*>(Kd + e * 16) = w;
  }
  __syncthreads();

  #pragma unroll
  for (int u = 0; u < 4; ++u) {
    int row = u * 16 + (tid >> 4);
    int col = 8 * (tid & 15);
    const float4* sp = reinterpret_cast<const float4*>(Vt + (size_t)row * DD + col);
    float4 x = sp[0], y = sp[1];
    *reinterpret_cast<float4*>(&st[row][col])     = x;
    *reinterpret_cast<float4*>(&st[row][col + 4]) = y;
  }
  __syncthreads();
  #pragma unroll
  for (int u = 0; u < 4; ++u) {
    int e = u * 256 + tid;
    int dg = e >> 8, s4 = (e >> 6) & 3, lane = e & 63;
    int h = lane >> 5, l31 = lane & 31;
    int d = dg * 32 + l31;
    int y8 = s4 * 2 + h;
    short8 w;
    #pragma unroll
    for (int j = 0; j < 8; ++j) {
      int a = ((y8 >> 2) << 5) | (((y8 >> 1) & 1) << 4) | ((j >> 2) << 3) | (j & 3) | ((y8 & 1) << 2);
      w[j] = f2bf(st[a][d]);
    }
    *reinterpret_cast<short8*>(Vd + e * 16) = w;
  }
}

// ---------------------------------------------------------------------------
// Main v9: zero LDS/barriers + in-wave software pipeline (T14):
//   - tile start: issue g1-K loads + ALL 16 V-fragment loads (hide under g0)
//   - before PV: prefetch next tile's g0-K into ping-pong regs
//   - ntile<=4 fully unrolled -> all register indexing static
// ---------------------------------------------------------------------------
__global__ __launch_bounds__(256) void sdpa_v9(
    const float* __restrict__ Q, const char* __restrict__ ws,
    float* __restrict__ O, unsigned short* __restrict__ partO,
    float* __restrict__ partML)
{
  const int y = blockIdx.x;
  const int b = y & 15;
  const int slot = y >> 4;
  const int i = SLOT_I[slot];
  const int c = slot - SLOT_BASE[i];
  const int nch = NCH[i];
  const int ntile = (c == nch - 1) ? (2 * i + 2 - 4 * c) : 4;
  const int kvt0 = 4 * c;
  const bool dostore = (nch == 1);

  const int tid  = threadIdx.x;
  const int lane = tid & 63;
  const int wid  = tid >> 6;
  const int l31  = lane & 31;
  const int h    = lane >> 5;

  const float* Qb  = Q + (size_t)b * SS * DD;
  const char*  Kws = ws + WS_K + ((size_t)(b * NKT)) * TILE_BYTES;
  const char*  Vws = ws + WS_V + ((size_t)(b * NKT)) * TILE_BYTES;

  const float qscale = 0.08838834764831845f * 1.4426950408889634f; // 1/sqrt(128)*log2e
  const int qg = 128 * i + wid * 32 + l31;

  // Q fragments (B-operand), scale folded
  short8 qf[8];
  {
    const float* qrow = Qb + (size_t)qg * DD;
    #pragma unroll
    for (int s = 0; s < 8; ++s) {
      const float4* p = reinterpret_cast<const float4*>(qrow + s * 16 + h * 8);
      float4 x = p[0], z = p[1];
      short8 w;
      w[0] = f2bf(x.x * qscale); w[1] = f2bf(x.y * qscale);
      w[2] = f2bf(x.z * qscale); w[3] = f2bf(x.w * qscale);
      w[4] = f2bf(z.x * qscale); w[5] = f2bf(z.y * qscale);
      w[6] = f2bf(z.z * qscale); w[7] = f2bf(z.w * qscale);
      qf[s] = w;
    }
  }

  f32x16 o[4];
  #pragma unroll
  for (int dg = 0; dg < 4; ++dg)
    #pragma unroll
    for (int r = 0; r < 16; ++r) o[dg][r] = 0.f;
  float lsum = 0.f;

  // QK+softmax for one 32-key group; returns group psum, packs P into w0,w1
  auto qk_group = [&](const short8 (&kf)[8], int tt, int g,
                      short8& w0, short8& w1) -> float {
    f32x16 acc;
    #pragma unroll
    for (int r = 0; r < 16; ++r) acc[r] = 0.f;
    __builtin_amdgcn_s_setprio(1);
    #pragma unroll
    for (int s = 0; s < 8; ++s)
      acc = __builtin_amdgcn_mfma_f32_32x32x16_bf16(kf[s], qf[s], acc, 0, 0, 0);
    __builtin_amdgcn_s_setprio(0);

    if (tt >= 2 * i) {                  // diagonal tile: causal mask
      const int kb = tt * 64 + g * 32 + 4 * h;
      #pragma unroll
      for (int r = 0; r < 16; ++r) {
        int keyg = kb + (r & 3) + 8 * (r >> 2);
        if (keyg > qg) acc[r] = -1e30f;
      }
    }

    float pg[16];
    #pragma unroll
    for (int r = 0; r < 16; ++r) pg[r] = exp2f(acc[r]);
    float s0 = ((pg[0]+pg[1])+(pg[2]+pg[3])) + ((pg[4]+pg[5])+(pg[6]+pg[7]));
    float s1 = ((pg[8]+pg[9])+(pg[10]+pg[11])) + ((pg[12]+pg[13])+(pg[14]+pg[15]));
    #pragma unroll
    for (int j = 0; j < 8; ++j) { w0[j] = f2bf(pg[j]); w1[j] = f2bf(pg[8 + j]); }
    return s0 + s1;
  };

  // ping-pong prefetch sets for g0-K fragments
  short8 kf0A[8], kf0B[8];
  {
    const char* Kt0 = Kws + (size_t)kvt0 * TILE_BYTES;
    #pragma unroll
    for (int s = 0; s < 8; ++s)
      kf0A[s] = *reinterpret_cast<const short8*>(Kt0 + s * 1024 + lane * 16);
  }

  #pragma unroll
  for (int t = 0; t < 4; ++t) {
    if (t < ntile) {
      const int tt = kvt0 + t;
      const char* Kt = Kws + (size_t)tt * TILE_BYTES;
      const char* Vt = Vws + (size_t)tt * TILE_BYTES;
      short8 (&kfc)[8] = ((t & 1) == 0) ? kf0A : kf0B;   // t literal -> static
      short8 (&kfn)[8] = ((t & 1) == 0) ? kf0B : kf0A;

      // issue-early: this tile's g1-K loads and ALL V-fragment loads
      short8 kf1[8];
      #pragma unroll
      for (int s = 0; s < 8; ++s)
        kf1[s] = *reinterpret_cast<const short8*>(Kt + 8192 + s * 1024 + lane * 16);
      short8 vf[16];
      #pragma unroll
      for (int e = 0; e < 16; ++e)
        vf[e] = *reinterpret_cast<const short8*>(Vt + e * 1024 + lane * 16);

      short8 pf[4];
      float psum;
      psum  = qk_group(kfc, tt, 0, pf[0], pf[1]);   // uses prefetched g0 set
      psum += qk_group(kf1, tt, 1, pf[2], pf[3]);   // g1 loads have drained by now
      lsum += psum;

      // prefetch next tile's g0-K (consumed next iteration)
      if (t + 1 < ntile) {
        const char* Ktn = Kws + (size_t)(tt + 1) * TILE_BYTES;
        #pragma unroll
        for (int s = 0; s < 8; ++s)
          kfn[s] = *reinterpret_cast<const short8*>(Ktn + s * 1024 + lane * 16);
      }

      // PV: O^T[d][q] += Vt . P
      __builtin_amdgcn_s_setprio(1);
      #pragma unroll
      for (int dg = 0; dg < 4; ++dg)
        #pragma unroll
        for (int s4 = 0; s4 < 4; ++s4)
          o[dg] = __builtin_amdgcn_mfma_f32_32x32x16_bf16(vf[dg * 4 + s4], pf[s4], o[dg], 0, 0, 0);
      __builtin_amdgcn_s_setprio(0);
    }
  }

  // ---- epilogue ----
  lsum += __shfl_xor(lsum, 32);

  if (dostore) {
    float inv = 1.0f / lsum;
    float* Ob = O + (size_t)b * SS * DD + (size_t)qg * DD;
    #pragma unroll
    for (int dg = 0; dg < 4; ++dg)
      #pragma unroll
      for (int rq = 0; rq < 4; ++rq) {
        int d0 = dg * 32 + 8 * rq + 4 * h;
        float4 w;
        w.x = o[dg][4 * rq + 0] * inv;
        w.y = o[dg][4 * rq + 1] * inv;
        w.z = o[dg][4 * rq + 2] * inv;
        w.w = o[dg][4 * rq + 3] * inv;
        *reinterpret_cast<float4*>(Ob + d0) = w;
      }
  } else {
    unsigned short* po = partO + (size_t)y * (128 * 128) + (size_t)(wid * 32 + l31) * 128;
    #pragma unroll
    for (int dg = 0; dg < 4; ++dg)
      #pragma unroll
      for (int rq = 0; rq < 4; ++rq) {
        int d0 = dg * 32 + 8 * rq + 4 * h;
        ushort4 u;
        u.x = f2bf(o[dg][4 * rq + 0]);
        u.y = f2bf(o[dg][4 * rq + 1]);
        u.z = f2bf(o[dg][4 * rq + 2]);
        u.w = f2bf(o[dg][4 * rq + 3]);
        *reinterpret_cast<ushort4*>(po + d0) = u;
      }
    if (h == 0) partML[y * 128 + wid * 32 + l31] = lsum;
  }
}

// ---------------------------------------------------------------------------
// Merge for i>=2: O[b][128i+row][:] = (sum_c U_c) / (sum_c l_c)
// ---------------------------------------------------------------------------
__global__ __launch_bounds__(256) void merge_v9(
    const unsigned short* __restrict__ partO, const float* __restrict__ partML,
    float* __restrict__ O)
{
  const int b = blockIdx.x;
  const int i = blockIdx.y + 2;
  const int rg = blockIdx.z;
  const int tid = threadIdx.x;
  const int row = rg * 32 + (tid >> 3);
  const int c0  = (tid & 7) * 16;

  float acc[16];
  #pragma unroll
  for (int u = 0; u < 16; ++u) acc[u] = 0.f;
  float ltot = 0.f;

  const int nch = NCH[i];
  const int base = SLOT_BASE[i];

  for (int c = 0; c < nch; ++c) {
    int slot = (base + c) * 16 + b;
    ltot += partML[slot * 128 + row];
    const uint4* po = reinterpret_cast<const uint4*>(
        partO + (size_t)slot * (128 * 128) + (size_t)row * 128 + c0);
    #pragma unroll
    for (int u = 0; u < 2; ++u) {
      uint4 v = po[u];
      acc[u*8+0] += bfbits2f(v.x << 16); acc[u*8+1] += bfbits2f(v.x & 0xffff0000u);
      acc[u*8+2] += bfbits2f(v.y << 16); acc[u*8+3] += bfbits2f(v.y & 0xffff0000u);
      acc[u*8+4] += bfbits2f(v.z << 16); acc[u*8+5] += bfbits2f(v.z & 0xffff0000u);
      acc[u*8+6] += bfbits2f(v.w << 16); acc[u*8+7] += bfbits2f(v.w & 0xffff0000u);
    }
  }
  float inv = 1.0f / ltot;
  float* orow = O + ((size_t)b * SS + 128 * i + row) * DD + c0;
  #pragma unroll
  for (int u = 0; u < 4; ++u) {
    float4 w;
    w.x = acc[4*u+0] * inv; w.y = acc[4*u+1] * inv;
    w.z = acc[4*u+2] * inv; w.w = acc[4*u+3] * inv;
    reinterpret_cast<float4*>(orow)[u] = w;
  }
}

// ---------------------------------------------------------------------------
// Emergency fallback (round-1 style, no ws) if workspace too small
// ---------------------------------------------------------------------------
__device__ __forceinline__ int sigma_col(int a) {
  return (a & 35) | ((a & 12) << 1) | ((a & 16) >> 2);
}

__global__ __launch_bounds__(256) void sdpa_naive(
    const float* __restrict__ Q, const float* __restrict__ K,
    const float* __restrict__ V, float* __restrict__ O)
{
  __shared__ __align__(16) char smem[64 * 128 * 2 * 2];
  char* Klds  = smem;
  char* Vtlds = smem + 64 * 128 * 2;

  const int b   = blockIdx.x;
  const int qb  = (int)gridDim.y - 1 - (int)blockIdx.y;
  const int q0  = qb * 64;
  const int tid = threadIdx.x;
  const int lane = tid & 63;
  const int wid  = tid >> 6;
  const int l15  = lane & 15;
  const int hi   = lane >> 4;

  const float* Qb = Q + (size_t)b * SS * DD;
  const float* Kb = K + (size_t)b * SS * DD;
  const float* Vb = V + (size_t)b * SS * DD;
  float*       Ob = O + (size_t)b * SS * DD;
  const float scale = 0.08838834764831845f;

  short8 qf[4];
  {
    const float* qrow = Qb + (size_t)(q0 + wid * 16 + l15) * DD;
    #pragma unroll
    for (int cc = 0; cc < 4; ++cc) {
      const float4* p = reinterpret_cast<const float4*>(qrow + 32 * cc + 8 * hi);
      float4 x = p[0], yv = p[1];
      short8 w;
      w[0]=f2bf(x.x*scale); w[1]=f2bf(x.y*scale); w[2]=f2bf(x.z*scale); w[3]=f2bf(x.w*scale);
      w[4]=f2bf(yv.x*scale); w[5]=f2bf(yv.y*scale); w[6]=f2bf(yv.z*scale); w[7]=f2bf(yv.w*scale);
      qf[cc] = w;
    }
  }

  f32x4 o[8];
  #pragma unroll
  for (int nt = 0; nt < 8; ++nt) o[nt] = (f32x4){0.f,0.f,0.f,0.f};
  float m = -INFINITY, lsum = 0.f;

  const int ntile = qb + 1;
  for (int t = 0; t < ntile; ++t) {
    const int kv0 = t * 64;
    if (t) __syncthreads();
    #pragma unroll
    for (int u = 0; u < 4; ++u) {
      int row = u * 16 + (tid >> 4);
      int col = 8 * (tid & 15);
      const float4* sp = reinterpret_cast<const float4*>(Kb + (size_t)(kv0 + row) * DD + col);
      float4 x = sp[0], yv = sp[1];
      short8 w;
      w[0]=f2bf(x.x); w[1]=f2bf(x.y); w[2]=f2bf(x.z); w[3]=f2bf(x.w);
      w[4]=f2bf(yv.x); w[5]=f2bf(yv.y); w[6]=f2bf(yv.z); w[7]=f2bf(yv.w);
      int off = (row * 256 + col * 2) ^ ((row & 7) << 4);
      *reinterpret_cast<short8*>(Klds + off) = w;
    }
    #pragma unroll
    for (int u = 0; u < 4; ++u) {
      int row = u * 16 + (tid >> 4);
      int col = 8 * (tid & 15);
      const float4* sp = reinterpret_cast<const float4*>(Vb + (size_t)(kv0 + row) * DD + col);
      float4 x = sp[0], yv = sp[1];
      int sc = sigma_col(row);
      float vals[8] = {x.x, x.y, x.z, x.w, yv.x, yv.y, yv.z, yv.w};
      #pragma unroll
      for (int j = 0; j < 8; ++j) {
        int d = col + j;
        int off = ((d << 7) + (sc << 1)) ^ ((((d >> 3) ^ d) & 7) << 4);
        *reinterpret_cast<unsigned short*>(Vtlds + off) = f2bf(vals[j]);
      }
    }
    __syncthreads();

    f32x4 sacc[4];
    #pragma unroll
    for (int g = 0; g < 4; ++g) {
      f32x4 acc = {0.f,0.f,0.f,0.f};
      #pragma unroll
      for (int cc = 0; cc < 4; ++cc) {
        int row = g * 16 + l15;
        int off = (row * 256 + (32 * cc + 8 * hi) * 2) ^ ((row & 7) << 4);
        short8 kf = *reinterpret_cast<const short8*>(Klds + off);
        acc = __builtin_amdgcn_mfma_f32_16x16x32_bf16(kf, qf[cc], acc, 0, 0, 0);
      }
      sacc[g] = acc;
    }
    if (t == ntile - 1) {
      const int q = q0 + wid * 16 + l15;
      #pragma unroll
      for (int g = 0; g < 4; ++g)
        #pragma unroll
        for (int ii = 0; ii < 4; ++ii) {
          int key = kv0 + g * 16 + 4 * hi + ii;
          if (key > q) sacc[g][ii] = -1e30f;
        }
    }
    float tmax = -INFINITY;
    #pragma unroll
    for (int g = 0; g < 4; ++g)
      #pragma unroll
      for (int ii = 0; ii < 4; ++ii) tmax = fmaxf(tmax, sacc[g][ii]);
    tmax = fmaxf(tmax, __shfl_xor(tmax, 16));
    tmax = fmaxf(tmax, __shfl_xor(tmax, 32));
    float mnew = fmaxf(m, tmax);
    float corr = __expf(m - mnew);
    m = mnew;
    float p[4][4]; float psum = 0.f;
    #pragma unroll
    for (int g = 0; g < 4; ++g)
      #pragma unroll
      for (int ii = 0; ii < 4; ++ii) {
        float pv = __expf(sacc[g][ii] - mnew);
        p[g][ii] = pv; psum += pv;
      }
    psum += __shfl_xor(psum, 16);
    psum += __shfl_xor(psum, 32);
    lsum = lsum * corr + psum;
    float corrO[4];
    #pragma unroll
    for (int ii = 0; ii < 4; ++ii) corrO[ii] = __shfl(corr, 4 * hi + ii);
    #pragma unroll
    for (int nt = 0; nt < 8; ++nt)
      #pragma unroll
      for (int ii = 0; ii < 4; ++ii) o[nt][ii] *= corrO[ii];
    short8 pfr[2];
    #pragma unroll
    for (int ks = 0; ks < 2; ++ks) {
      short8 w;
      #pragma unroll
      for (int ii = 0; ii < 4; ++ii) { w[ii] = f2bf(p[2*ks][ii]); w[4+ii] = f2bf(p[2*ks+1][ii]); }
      pfr[ks] = w;
    }
    #pragma unroll
    for (int ks = 0; ks < 2; ++ks)
      #pragma unroll
      for (int nt = 0; nt < 8; ++nt) {
        int d = nt * 16 + l15;
        int off = ((d << 7) + (ks * 32 + 8 * hi) * 2) ^ ((((d >> 3) ^ d) & 7) << 4);
        short8 vvf = *reinterpret_cast<const short8*>(Vtlds + off);
        o[nt] = __builtin_amdgcn_mfma_f32_16x16x32_bf16(pfr[ks], vvf, o[nt], 0, 0, 0);
      }
  }
  float rl = 1.0f / lsum;
  float rlO[4];
  #pragma unroll
  for (int ii = 0; ii < 4; ++ii) rlO[ii] = __shfl(rl, 4 * hi + ii);
  const int qrow = q0 + wid * 16;
  #pragma unroll
  for (int nt = 0; nt < 8; ++nt)
    #pragma unroll
    for (int ii = 0; ii < 4; ++ii)
      Ob[(size_t)(qrow + 4 * hi + ii) * DD + nt * 16 + l15] = o[nt][ii] * rlO[ii];
}

extern "C" void kernel_launch(void* const* d_in, const int* in_sizes, int n_in,
                              void* d_out, int out_size, void* d_ws, size_t ws_size,
                              hipStream_t stream) {
  const float* Q = (const float*)d_in[0];
  const float* K = (const float*)d_in[1];
  const float* V = (const float*)d_in[2];
  float* O = (float*)d_out;
  char* ws = (char*)d_ws;

  if (ws_size >= WS_NEED) {
    unsigned short* partO = (unsigned short*)(ws + WS_PO);
    float* partML = (float*)(ws + WS_ML);
    prepack_kv9<<<dim3(16, NKT), 256, 0, stream>>>(K, V, ws);
    sdpa_v9<<<dim3(NBLK), 256, 0, stream>>>(Q, ws, O, partO, partML);
    merge_v9<<<dim3(16, 14, 4), 256, 0, stream>>>(partO, partML, O);
  } else {
    sdpa_naive<<<dim3(16, 32), 256, 0, stream>>>(Q, K, V, O);
  }
}